// Round 9
// baseline (247.265 us; speedup 1.0000x reference)
//
#include <hip/hip_runtime.h>
#include <math.h>
#include <stdint.h>

// ---------------- Problem constants ----------------
#define E_N     7
#define BATCH   32768
#define STATE_D 32
#define ACT_D   8
#define DOUT    32

typedef _Float16 f16;
typedef __attribute__((ext_vector_type(4)))  _Float16 f16x4;
typedef __attribute__((ext_vector_type(8)))  _Float16 f16x8;
typedef __attribute__((ext_vector_type(16))) float    f32x16;

// ---------------- ws layout (f16 elements), fragment-packed ----------------
// slice = one [64 lane][8 elem] fragment-tile group (512 f16 = 1KB)
// frag (nt,kt): lane l holds W[k = kt*16 + (l>>5)*8 + j][n = nt*32 + (l&31)]
// Serves as MFMA A-frag (row=n) or B-frag (col=n) identically.
#define OFF_L0  0           // e-stride 16384  (8nt*4kt*512)
#define OFF_L1  114688      // e-stride 65536  (8*16*512)
#define OFF_L2  573440
#define OFF_L3  1032192     // e-stride 32768  (4*16*512)
#define OFF_H   1261568     // e-stride 8192   (2*8*512)
#define WS_ELEMS 1318912
#define WS_NEED  ((size_t)WS_ELEMS*2)

// ---------------- fast math (hardware trans ops only, no libm) ----------------
__device__ __forceinline__ float swish_f(float x) {
    float t = __expf(-x);
    return x * __builtin_amdgcn_rcpf(1.0f + t);
}
__device__ __forceinline__ float softplus_fast(float z) {
    float sp = __logf(1.0f + __expf(z));   // z>88: inf -> select takes z
    return (z > 20.0f) ? z : sp;
}
__device__ __forceinline__ float soft_clamp_f(float x, float mn, float mx) {
    x = mx - softplus_fast(mx - x);
    x = mn + softplus_fast(x - mn);
    return x;
}

// ============================================================================
// Prep: pack weights into fp16 fragment order (unchanged, known-correct).
// ============================================================================
#define PREP_THREADS 164864   // 2576 slices * 64 lanes
__global__ __launch_bounds__(256) void prep_f16(
    const float* __restrict__ W0, const float* __restrict__ W1,
    const float* __restrict__ W2, const float* __restrict__ W3,
    const float* __restrict__ Wmu, const float* __restrict__ Wsg,
    unsigned short* __restrict__ ws)
{
    int t = blockIdx.x * 256 + threadIdx.x;
    if (t >= PREP_THREADS) return;
    int slice = t >> 6, l = t & 63;
    int l31 = l & 31, lg = l >> 5;
    const float* src; int e, nt, kt, Ksrc, N; bool head = false;
    if (slice < 224)       { int r = slice;      e=r>>5; r&=31;  nt=r>>2; kt=r&3;  src=W0; Ksrc=40;  N=256; }
    else if (slice < 1120) { int r = slice-224;  e=r>>7; r&=127; nt=r>>4; kt=r&15; src=W1; Ksrc=256; N=256; }
    else if (slice < 2016) { int r = slice-1120; e=r>>7; r&=127; nt=r>>4; kt=r&15; src=W2; Ksrc=256; N=256; }
    else if (slice < 2464) { int r = slice-2016; e=r>>6; r&=63;  nt=r>>4; kt=r&15; src=W3; Ksrc=256; N=128; }
    else                   { int r = slice-2464; e=r>>4; r&=15;  nt=r>>3; kt=r&7;
                             src = (nt==0) ? Wmu : Wsg; Ksrc=128; N=32; head=true; }
    int n  = head ? l31 : nt*32 + l31;
    int k0 = kt*16 + lg*8;
    f16x8 v;
    #pragma unroll
    for (int j = 0; j < 8; ++j) {
        int k = k0 + j;
        float x = (k < Ksrc) ? src[(e*Ksrc + k)*N + n] : 0.0f;
        v[j] = (f16)x;
    }
    *reinterpret_cast<f16x8*>(ws + (size_t)slice*512 + l*8) = v;
}

// ============================================================================
// Hidden layer, 8-wave version: each wave owns ONE m-tile (mt) and NTW n-tiles.
// acc = NTW x f32x16 (32 AGPR max) -> fits 128-reg/wave budget at 4 waves/EU.
// In-place safe: all reads before barrier 1, writes after, barrier 2 publishes.
// ============================================================================
template<int KT, int NTW, int ASTR, int SWZM>
__device__ __forceinline__ void layer_sw8(
    const unsigned short* __restrict__ Wf, const float* __restrict__ bias,
    const unsigned short* __restrict__ aBuf, unsigned short* __restrict__ dBuf,
    int nt0, int mt, int lane)
{
    const int l31 = lane & 31, lg = lane >> 5;
    f32x16 acc[NTW];
    #pragma unroll
    for (int jj = 0; jj < NTW; ++jj)
        #pragma unroll
        for (int r = 0; r < 16; ++r) acc[jj][r] = 0.0f;

    const int arow = mt*32 + l31;
    const int ab = arow * ASTR;
    const int sw = arow & SWZM;

    #pragma unroll
    for (int kt = 0; kt < KT; ++kt) {
        const int kg = kt*2 + lg;
        f16x8 a = *reinterpret_cast<const f16x8*>(aBuf + ab + ((kg ^ sw) << 3));
        #pragma unroll
        for (int jj = 0; jj < NTW; ++jj) {
            f16x8 w = *reinterpret_cast<const f16x8*>(Wf + (nt0+jj)*KT*512 + kt*512 + lane*8);
            acc[jj] = __builtin_amdgcn_mfma_f32_32x32x16_f16(w, a, acc[jj], 0, 0, 0);
        }
    }
    __syncthreads();   // all reads of aBuf complete -> safe to overwrite in place
    {
        const int m  = mt*32 + l31;
        const int rb = m*256, swd = m & 15;
        #pragma unroll
        for (int jj = 0; jj < NTW; ++jj) {
            const int nb = (nt0+jj)*32 + 4*lg;
            #pragma unroll
            for (int g = 0; g < 4; ++g) {
                float4 bv = *reinterpret_cast<const float4*>(&bias[nb + 8*g]);
                f16x4 pk;
                pk[0] = (f16)swish_f(acc[jj][4*g+0] + bv.x);
                pk[1] = (f16)swish_f(acc[jj][4*g+1] + bv.y);
                pk[2] = (f16)swish_f(acc[jj][4*g+2] + bv.z);
                pk[3] = (f16)swish_f(acc[jj][4*g+3] + bv.w);
                const int cg = (nt0+jj)*4 + g;
                *reinterpret_cast<f16x4*>(dBuf + rb + ((cg ^ swd) << 3) + 4*lg) = pk;
            }
        }
    }
    __syncthreads();
}

// ============================================================================
// L0 direct-from-global, 8-wave: one mt per wave, x-frags in registers.
// ============================================================================
template<int NTW>
__device__ __forceinline__ void layer0_direct8(
    const unsigned short* __restrict__ Wf, const float* __restrict__ bias,
    const float* __restrict__ gs, const float* __restrict__ ga,
    unsigned short* __restrict__ dBuf, int brow0, int nt0, int mt, int lane)
{
    const int l31 = lane & 31, lg = lane >> 5;
    const int row = brow0 + mt*32 + l31;
    f16x8 xf[3];
    #pragma unroll
    for (int kt = 0; kt < 2; ++kt) {
        const float* p = &gs[(size_t)row*STATE_D + kt*16 + lg*8];
        float4 q0 = *reinterpret_cast<const float4*>(p);
        float4 q1 = *reinterpret_cast<const float4*>(p + 4);
        f16x8 v;
        v[0]=(f16)q0.x; v[1]=(f16)q0.y; v[2]=(f16)q0.z; v[3]=(f16)q0.w;
        v[4]=(f16)q1.x; v[5]=(f16)q1.y; v[6]=(f16)q1.z; v[7]=(f16)q1.w;
        xf[kt] = v;
    }
    {
        f16x8 v;
        if (lg == 0) {
            const float* p = &ga[(size_t)row*ACT_D];
            float4 q0 = *reinterpret_cast<const float4*>(p);
            float4 q1 = *reinterpret_cast<const float4*>(p + 4);
            v[0]=(f16)q0.x; v[1]=(f16)q0.y; v[2]=(f16)q0.z; v[3]=(f16)q0.w;
            v[4]=(f16)q1.x; v[5]=(f16)q1.y; v[6]=(f16)q1.z; v[7]=(f16)q1.w;
        } else {
            #pragma unroll
            for (int i = 0; i < 8; ++i) v[i] = (f16)0.0f;
        }
        xf[2] = v;
    }
    f32x16 acc[NTW];
    #pragma unroll
    for (int jj = 0; jj < NTW; ++jj)
        #pragma unroll
        for (int r = 0; r < 16; ++r) acc[jj][r] = 0.0f;
    #pragma unroll
    for (int kt = 0; kt < 3; ++kt) {     // kt=3 is zero-pad, skipped
        #pragma unroll
        for (int jj = 0; jj < NTW; ++jj) {
            f16x8 w = *reinterpret_cast<const f16x8*>(Wf + (nt0+jj)*4*512 + kt*512 + lane*8);
            acc[jj] = __builtin_amdgcn_mfma_f32_32x32x16_f16(w, xf[kt], acc[jj], 0, 0, 0);
        }
    }
    {
        const int m  = mt*32 + l31;
        const int rb = m*256, swd = m & 15;
        #pragma unroll
        for (int jj = 0; jj < NTW; ++jj) {
            const int nb = (nt0+jj)*32 + 4*lg;
            #pragma unroll
            for (int g = 0; g < 4; ++g) {
                float4 bv = *reinterpret_cast<const float4*>(&bias[nb + 8*g]);
                f16x4 pk;
                pk[0] = (f16)swish_f(acc[jj][4*g+0] + bv.x);
                pk[1] = (f16)swish_f(acc[jj][4*g+1] + bv.y);
                pk[2] = (f16)swish_f(acc[jj][4*g+2] + bv.z);
                pk[3] = (f16)swish_f(acc[jj][4*g+3] + bv.w);
                const int cg = (nt0+jj)*4 + g;
                *reinterpret_cast<f16x4*>(dBuf + rb + ((cg ^ swd) << 3) + 4*lg) = pk;
            }
        }
    }
    __syncthreads();   // hbuf ready for L1
}

// 8 waves x 512 thr, BM=64 (same W-reuse as before -> L2 traffic unchanged).
// Per-wave state: acc 32 AGPR + ~80 arch VGPR <= 128 -> 4 waves/EU (2 blocks/CU,
// 16 waves/CU vs round-8's 9.5). launch_bounds(512,4): cap = 512-reg pool / 4.
__global__ __launch_bounds__(512, 4) void ens16(
    const float* __restrict__ gs, const float* __restrict__ ga,
    const unsigned short* __restrict__ ws,
    const float* __restrict__ b0, const float* __restrict__ b1,
    const float* __restrict__ b2, const float* __restrict__ b3,
    const float* __restrict__ bmu, const float* __restrict__ bsg,
    const float* __restrict__ mxl, const float* __restrict__ mnl,
    float* __restrict__ out)
{
    __shared__ unsigned short hbuf[64*256];  // 32 KB

    const int tid = threadIdx.x, lane = tid & 63, wv = tid >> 6;
    const int e = blockIdx.x >> 9;
    const int brow0 = (blockIdx.x & 511) << 6;
    const int mt  = wv & 1;        // m-tile owned by this wave
    const int ntp = wv >> 1;       // n-tile group (0..3)

    // ---- layer chain ----
    layer0_direct8<2>(ws + OFF_L0 + e*16384, b0 + e*256, gs, ga, hbuf, brow0, ntp*2, mt, lane);
    layer_sw8<16,2, 256,15>(ws + OFF_L1 + e*65536, b1 + e*256, hbuf, hbuf, ntp*2, mt, lane);
    layer_sw8<16,2, 256,15>(ws + OFF_L2 + e*65536, b2 + e*256, hbuf, hbuf, ntp*2, mt, lane);
    layer_sw8<16,1, 256,15>(ws + OFF_L3 + e*32768, b3 + e*128, hbuf, hbuf, ntp,  mt, lane);

    // ---- heads: 4 tiles (2 mt x {mu,sig}) on waves 0-3; waves 4-7 done ----
    if (wv >= 4) return;
    {
        const unsigned short* WH = ws + OFF_H + e*8192;
        const int mtH = wv >> 1, ntH = wv & 1;
        const int l31 = lane & 31, lg = lane >> 5;
        float bvH = (ntH == 0) ? bmu[e*32 + l31] : bsg[e*32 + l31];
        f32x16 acc;
        #pragma unroll
        for (int r = 0; r < 16; ++r) acc[r] = bvH;
        const unsigned short* wpH = WH + ntH*8*512 + lane*8;
        const int row0 = mtH*32 + l31, ab = row0*256, sw = row0 & 15;
        #pragma unroll
        for (int kt = 0; kt < 8; ++kt) {
            int kg = kt*2 + lg;
            f16x8 ac = *reinterpret_cast<const f16x8*>(hbuf + ab + ((kg ^ sw) << 3));
            f16x8 bc = *reinterpret_cast<const f16x8*>(wpH + kt*512);
            acc = __builtin_amdgcn_mfma_f32_32x32x16_f16(ac, bc, acc, 0, 0, 0);
        }
        if (ntH == 0) {
            #pragma unroll
            for (int r = 0; r < 16; ++r) {
                int grow = brow0 + mtH*32 + (r & 3) + 8*(r >> 2) + 4*lg;
                float v = acc[r] + gs[(size_t)grow*32 + l31];
                __builtin_nontemporal_store(v, &out[((size_t)e*BATCH + grow)*32 + l31]);
            }
        } else {
            float mx = mxl[l31], mn = mnl[l31];
            #pragma unroll
            for (int r = 0; r < 16; ++r) {
                int grow = brow0 + mtH*32 + (r & 3) + 8*(r >> 2) + 4*lg;
                float v = __expf(soft_clamp_f(acc[r], mn, mx));
                __builtin_nontemporal_store(v,
                    &out[(size_t)E_N*BATCH*32 + ((size_t)e*BATCH + grow)*32 + l31]);
            }
        }
    }
}

// ============================================================================
// Fallback fp32 kernel (round-0, known-correct) in case ws is too small
// ============================================================================
#define TILE_B  64
#define THREADS 256
#define LDH     260
#define LDX     44
__device__ __forceinline__ float f4c(const float4& v, int i) {
    return reinterpret_cast<const float*>(&v)[i];
}
__device__ __forceinline__ float softplus_ref(float z) {
    return (z > 20.0f) ? z : log1pf(expf(z));
}
__device__ __forceinline__ float soft_clamp_ref(float x, float mn, float mx) {
    x = mx - softplus_ref(mx - x);
    x = mn + softplus_ref(x - mn);
    return x;
}
template<int K, int N, int LDIN, bool SW>
__device__ __forceinline__ void layer_fn(const float* __restrict__ lin,
                                         float* __restrict__ lout,
                                         const float* __restrict__ W,
                                         const float* __restrict__ bias,
                                         int tx, int ty)
{
    constexpr int CH = N / 64;
    float4 acc[4][CH];
    #pragma unroll
    for (int jj = 0; jj < CH; ++jj) {
        float4 bv = *reinterpret_cast<const float4*>(&bias[jj*64 + tx*4]);
        #pragma unroll
        for (int r = 0; r < 4; ++r) acc[r][jj] = bv;
    }
    for (int k0 = 0; k0 < K; k0 += 4) {
        float4 a[4];
        #pragma unroll
        for (int r = 0; r < 4; ++r)
            a[r] = *reinterpret_cast<const float4*>(&lin[(ty*4 + r)*LDIN + k0]);
        #pragma unroll
        for (int kk = 0; kk < 4; ++kk) {
            float4 w[CH];
            #pragma unroll
            for (int jj = 0; jj < CH; ++jj)
                w[jj] = *reinterpret_cast<const float4*>(&W[(k0+kk)*N + jj*64 + tx*4]);
            #pragma unroll
            for (int r = 0; r < 4; ++r) {
                float av = f4c(a[r], kk);
                #pragma unroll
                for (int jj = 0; jj < CH; ++jj) {
                    acc[r][jj].x = fmaf(av, w[jj].x, acc[r][jj].x);
                    acc[r][jj].y = fmaf(av, w[jj].y, acc[r][jj].y);
                    acc[r][jj].z = fmaf(av, w[jj].z, acc[r][jj].z);
                    acc[r][jj].w = fmaf(av, w[jj].w, acc[r][jj].w);
                }
            }
        }
    }
    __syncthreads();
    #pragma unroll
    for (int r = 0; r < 4; ++r) {
        #pragma unroll
        for (int jj = 0; jj < CH; ++jj) {
            float4 v = acc[r][jj];
            if (SW) { v.x = swish_f(v.x); v.y = swish_f(v.y); v.z = swish_f(v.z); v.w = swish_f(v.w); }
            *reinterpret_cast<float4*>(&lout[(ty*4 + r)*LDH + jj*64 + tx*4]) = v;
        }
    }
    __syncthreads();
}
__global__ __launch_bounds__(THREADS, 2)
void ens_fwd(const float* __restrict__ g_state, const float* __restrict__ g_action,
             const float* __restrict__ W0, const float* __restrict__ b0,
             const float* __restrict__ W1, const float* __restrict__ b1,
             const float* __restrict__ W2, const float* __restrict__ b2,
             const float* __restrict__ W3, const float* __restrict__ b3,
             const float* __restrict__ Wmu, const float* __restrict__ bmu,
             const float* __restrict__ Wsg, const float* __restrict__ bsg,
             const float* __restrict__ mxl, const float* __restrict__ mnl,
             float* __restrict__ out)
{
    __shared__ float h[TILE_B * LDH];
    __shared__ float xb[TILE_B * LDX];
    const int tid  = threadIdx.x;
    const int tx   = tid & 15;
    const int ty   = tid >> 4;
    const int e    = blockIdx.x / (BATCH / TILE_B);
    const int brow0 = (blockIdx.x % (BATCH / TILE_B)) * TILE_B;
    for (int i = tid; i < TILE_B * 8; i += THREADS) {
        int r = i >> 3, c = (i & 7) << 2;
        *reinterpret_cast<float4*>(&xb[r*LDX + c]) =
            *reinterpret_cast<const float4*>(&g_state[(size_t)(brow0 + r)*STATE_D + c]);
    }
    if (tid < TILE_B * 2) {
        int r = tid >> 1, c = (tid & 1) << 2;
        *reinterpret_cast<float4*>(&xb[r*LDX + STATE_D + c]) =
            *reinterpret_cast<const float4*>(&g_action[(size_t)(brow0 + r)*ACT_D + c]);
    }
    __syncthreads();
    layer_fn<40,  256, LDX, true>(xb, h, W0 + e*40*256,  b0 + e*256, tx, ty);
    layer_fn<256, 256, LDH, true>(h,  h, W1 + e*256*256, b1 + e*256, tx, ty);
    layer_fn<256, 256, LDH, true>(h,  h, W2 + e*256*256, b2 + e*256, tx, ty);
    layer_fn<256, 128, LDH, true>(h,  h, W3 + e*256*128, b3 + e*128, tx, ty);
    const float* Wm = Wmu + e*128*32;
    const float* Ws = Wsg + e*128*32;
    float2 am[4], as[4];
    {
        float2 bm = *reinterpret_cast<const float2*>(&bmu[e*32 + tx*2]);
        float2 bs = *reinterpret_cast<const float2*>(&bsg[e*32 + tx*2]);
        #pragma unroll
        for (int r = 0; r < 4; ++r) { am[r] = bm; as[r] = bs; }
    }
    for (int k0 = 0; k0 < 128; k0 += 4) {
        float4 a[4];
        #pragma unroll
        for (int r = 0; r < 4; ++r)
            a[r] = *reinterpret_cast<const float4*>(&h[(ty*4 + r)*LDH + k0]);
        #pragma unroll
        for (int kk = 0; kk < 4; ++kk) {
            float2 wm = *reinterpret_cast<const float2*>(&Wm[(k0+kk)*32 + tx*2]);
            float2 ws2 = *reinterpret_cast<const float2*>(&Ws[(k0+kk)*32 + tx*2]);
            #pragma unroll
            for (int r = 0; r < 4; ++r) {
                float av = f4c(a[r], kk);
                am[r].x = fmaf(av, wm.x, am[r].x);
                am[r].y = fmaf(av, wm.y, am[r].y);
                as[r].x = fmaf(av, ws2.x, as[r].x);
                as[r].y = fmaf(av, ws2.y, as[r].y);
            }
        }
    }
    const float2 mx = *reinterpret_cast<const float2*>(&mxl[tx*2]);
    const float2 mn = *reinterpret_cast<const float2*>(&mnl[tx*2]);
    #pragma unroll
    for (int r = 0; r < 4; ++r) {
        const int row = brow0 + ty*4 + r;
        float2 st = *reinterpret_cast<const float2*>(&g_state[(size_t)row*STATE_D + tx*2]);
        float2 mu; mu.x = am[r].x + st.x; mu.y = am[r].y + st.y;
        float2 sg;
        sg.x = expf(soft_clamp_ref(as[r].x, mn.x, mx.x));
        sg.y = expf(soft_clamp_ref(as[r].y, mn.y, mx.y));
        size_t idx = ((size_t)e*BATCH + row)*DOUT + tx*2;
        *reinterpret_cast<float2*>(&out[idx]) = mu;
        *reinterpret_cast<float2*>(&out[(size_t)E_N*BATCH*DOUT + idx]) = sg;
    }
}

// ============================================================================
extern "C" void kernel_launch(void* const* d_in, const int* in_sizes, int n_in,
                              void* d_out, int out_size, void* d_ws, size_t ws_size,
                              hipStream_t stream) {
    (void)in_sizes; (void)n_in; (void)out_size;
    const float* state  = (const float*)d_in[0];
    const float* action = (const float*)d_in[1];
    const float* W0  = (const float*)d_in[2];
    const float* b0  = (const float*)d_in[3];
    const float* W1  = (const float*)d_in[4];
    const float* b1  = (const float*)d_in[5];
    const float* W2  = (const float*)d_in[6];
    const float* b2  = (const float*)d_in[7];
    const float* W3  = (const float*)d_in[8];
    const float* b3  = (const float*)d_in[9];
    const float* Wmu = (const float*)d_in[10];
    const float* bmu = (const float*)d_in[11];
    const float* Wsg = (const float*)d_in[12];
    const float* bsg = (const float*)d_in[13];
    const float* mxl = (const float*)d_in[14];
    const float* mnl = (const float*)d_in[15];
    float* out = (float*)d_out;

    if (ws_size >= WS_NEED) {
        unsigned short* ws = (unsigned short*)d_ws;
        prep_f16<<<dim3((PREP_THREADS + 255)/256), dim3(256), 0, stream>>>(
            W0, W1, W2, W3, Wmu, Wsg, ws);
        ens16<<<dim3(E_N * 512), dim3(512), 0, stream>>>(
            state, action, ws, b0, b1, b2, b3, bmu, bsg, mxl, mnl, out);
    } else {
        ens_fwd<<<dim3(E_N * (BATCH/TILE_B)), dim3(THREADS), 0, stream>>>(
            state, action, W0, b0, W1, b1, W2, b2, W3, b3,
            Wmu, bmu, Wsg, bsg, mxl, mnl, out);
    }
}